// Round 7
// baseline (272.444 us; speedup 1.0000x reference)
//
#include <hip/hip_runtime.h>
#include <hip/hip_bf16.h>
#include <cstddef>

constexpr int B = 32, E = 30000, D = 200, L = 50;

using short8 = __attribute__((ext_vector_type(8))) short;
using f32x4  = __attribute__((ext_vector_type(4))) float;
using uint4v = __attribute__((ext_vector_type(4))) unsigned int;

__device__ __forceinline__ float sigmoidf_(float x){ return 1.f/(1.f+__expf(-x)); }
__device__ __forceinline__ float tanhf_(float x){
    float t = __expf(-2.f*fabsf(x));
    return copysignf((1.f-t)/(1.f+t), x);
}
// round-to-nearest-even f32 -> bf16 bits (used by wprep; any accurate split works)
__device__ __forceinline__ unsigned short f2bf(float x){
    unsigned u = __float_as_uint(x);
    u += 0x7fffu + ((u>>16)&1u);
    return (unsigned short)(u>>16);
}
__device__ __forceinline__ float bf2f(unsigned short h){
    return __uint_as_float(((unsigned)h)<<16);
}

// In-register hi/lo bf16 split of 8 floats (truncation split, err ~2^-16 rel).
// perm(u1,u0,0x07060302) packs the two high-16s as (h0 low, h1 high).
__device__ __forceinline__ void split8(const float* v, short8& hv, short8& lv) {
    uint4v hp, lp;
    #pragma unroll
    for (int z = 0; z < 4; ++z) {
        unsigned u0 = __float_as_uint(v[2*z]), u1 = __float_as_uint(v[2*z+1]);
        hp[z] = __builtin_amdgcn_perm(u1, u0, 0x07060302u);
        float r0 = v[2*z]   - __uint_as_float(u0 & 0xFFFF0000u);
        float r1 = v[2*z+1] - __uint_as_float(u1 & 0xFFFF0000u);
        lp[z] = __builtin_amdgcn_perm(__float_as_uint(r1), __float_as_uint(r0), 0x07060302u);
    }
    hv = __builtin_bit_cast(short8, hp);
    lv = __builtin_bit_cast(short8, lp);
}

// ---------------------------------------------------------------------------
// W-prep: W' hi/lo bf16 planes in MFMA B-frag order.
//   n = mat*208 + d  (26 n-tiles of 16); k padded to 256.
//   elem(nt,ks,lane,j) = W[n=nt*16+(lane&15)][k=ks*32+((lane>>4)&3)*8+j]
// ---------------------------------------------------------------------------
constexpr int WELEMS = 26*8*64*8;  // 106496

__global__ __launch_bounds__(256) void wprep_kernel(
    const float* __restrict__ Wg, const float* __restrict__ W1,
    const float* __restrict__ W2,
    unsigned short* __restrict__ whi, unsigned short* __restrict__ wlo)
{
    int idx = blockIdx.x*256 + threadIdx.x;
    if (idx >= WELEMS) return;
    int j = idx & 7, l = (idx>>3)&63, ks = (idx>>9)&7, nt = idx>>12;
    int n = nt*16 + (l&15);
    int k = ks*32 + ((l>>4)&3)*8 + j;
    float v = 0.f;
    if (n < 208) {
        int d = n;
        if (d < 200 && k < 250) v = Wg[d*250 + k];
    } else {
        int d = n - 208;
        if (d < 200) {
            if (k < 200)      v = W1[d*200 + k];
            else if (k < 250) v = W2[d*50 + (k-200)];
        }
    }
    unsigned short h = f2bf(v);
    whi[idx] = h;
    wlo[idx] = f2bf(v - bf2f(h));
}

// ---------------------------------------------------------------------------
// sums: 256 blocks (32 b x 8 e-chunks) -> psum8/isum8 partials
// ---------------------------------------------------------------------------
__global__ __launch_bounds__(256) void sums_kernel(
    const int* __restrict__ e2m, const float* __restrict__ prob,
    float* __restrict__ psum8, float* __restrict__ isum8)
{
    const int tid = threadIdx.x;
    const int b = blockIdx.x >> 3, ch = blockIdx.x & 7;
    const int es = ch * 3750;
    const int*   mrow = e2m  + (size_t)b * E + es;
    const float* prow = prob + (size_t)b * E + es;
    float sp = 0.f, si = 0.f;
    for (int i = tid; i < 3750; i += 256) {
        float m = (float)mrow[i];
        sp = fmaf(m, prow[i], sp);
        si += (1.f - m);
    }
    #pragma unroll
    for (int off = 32; off >= 1; off >>= 1) {
        sp += __shfl_down(sp, off);
        si += __shfl_down(si, off);
    }
    __shared__ float rp[4], ri[4];
    if ((tid & 63) == 0) { rp[tid >> 6] = sp; ri[tid >> 6] = si; }
    __syncthreads();
    if (tid == 0) {
        psum8[b*8 + ch] = rp[0] + rp[1] + rp[2] + rp[3];
        isum8[b*8 + ch] = ri[0] + ri[1] + ri[2] + ri[3];
    }
}

// ---------------------------------------------------------------------------
// Gate v4: no A-LDS, no main-loop barriers.
//   Grid 944 = 472 m-blocks (64 rows) x 2 n-halves; 512 thr = 8 waves
//   (mt 0..3 x g 0..1). Each lane loads its own A-frag from global (L1
//   dedupes g=0/1), splits hi/lo in-register; W' depth-1 prefetched.
//   Epilogue: single barrier, g=1 passes pre2 via LDS, g=0 combines.
// ---------------------------------------------------------------------------
__global__ __launch_bounds__(512) void gate_kernel(
    const float* __restrict__ emb_e, const float* __restrict__ num_lit,
    const unsigned short* __restrict__ whi, const unsigned short* __restrict__ wlo,
    const float* __restrict__ bg, const float* __restrict__ gbias,
    float* __restrict__ e2_emb)
{
    __shared__ __align__(16) float PW[4*7*64*4];   // 28 KB epilogue exchange

    const int tid  = threadIdx.x;
    const int lane = tid & 63;
    const int wid  = tid >> 6;
    const int mt   = wid & 3;
    const int g    = wid >> 2;
    const int mb   = blockIdx.x >> 1;
    const int h    = blockIdx.x & 1;
    const int e0   = mb * 64;
    const int start = h * 6;
    const int ntb  = start + g * 13;

    const int arow = e0 + mt*16 + (lane & 15);
    const int kgrp = ((lane >> 4) & 3) * 8;
    const bool rok = arow < E;
    const float* aeb = emb_e   + (size_t)arow * 200;
    const float* alb = num_lit + (size_t)arow * 50;

    f32x4 acc[7];
    #pragma unroll
    for (int i = 0; i < 7; ++i) acc[i] = (f32x4){0.f,0.f,0.f,0.f};

#define WOFF(p, ks) (((size_t)(((ntb + (p))*8 + c*2 + (ks))*64 + lane))*8)

    for (int c = 0; c < 4; ++c) {
        // ---- per-lane A fragment load + hi/lo split ----
        short8 xh[2], xl[2];
        #pragma unroll
        for (int ks = 0; ks < 2; ++ks) {
            const int k0 = c*64 + ks*32 + kgrp;       // multiple of 8
            float v[8];
            if (rok && k0 <= 192) {
                float4 f0 = *(const float4*)(aeb + k0);
                float4 f1 = *(const float4*)(aeb + k0 + 4);
                v[0]=f0.x; v[1]=f0.y; v[2]=f0.z; v[3]=f0.w;
                v[4]=f1.x; v[5]=f1.y; v[6]=f1.z; v[7]=f1.w;
            } else if (rok && k0 <= 240) {            // num_lit, full octet
                const int kl = k0 - 200;
                #pragma unroll
                for (int z = 0; z < 4; ++z) {
                    float2 f = *(const float2*)(alb + kl + 2*z);
                    v[2*z] = f.x; v[2*z+1] = f.y;
                }
            } else if (rok && k0 == 248) {            // tail: 2 valid
                float2 f = *(const float2*)(alb + 48);
                v[0] = f.x; v[1] = f.y;
                #pragma unroll
                for (int z = 2; z < 8; ++z) v[z] = 0.f;
            } else {
                #pragma unroll
                for (int z = 0; z < 8; ++z) v[z] = 0.f;
            }
            split8(v, xh[ks], xl[ks]);
        }

        // ---- W' depth-1 prefetch + MFMA ----
        short8 pwh[2][2], pwl[2][2];
        pwh[0][0] = *(const short8*)(whi + WOFF(0,0));
        pwh[0][1] = *(const short8*)(whi + WOFF(0,1));
        pwl[0][0] = *(const short8*)(wlo + WOFF(0,0));
        pwl[0][1] = *(const short8*)(wlo + WOFF(0,1));

        #pragma unroll
        for (int p = 0; p < 7; ++p) {
            const int cur = p & 1, nxt = cur ^ 1;
            if (p < 6) {
                pwh[nxt][0] = *(const short8*)(whi + WOFF(p+1,0));
                pwh[nxt][1] = *(const short8*)(whi + WOFF(p+1,1));
                pwl[nxt][0] = *(const short8*)(wlo + WOFF(p+1,0));
                pwl[nxt][1] = *(const short8*)(wlo + WOFF(p+1,1));
            }
            #pragma unroll
            for (int ks = 0; ks < 2; ++ks) {
                acc[p] = __builtin_amdgcn_mfma_f32_16x16x32_bf16(xh[ks], pwh[cur][ks], acc[p], 0,0,0);
                acc[p] = __builtin_amdgcn_mfma_f32_16x16x32_bf16(xl[ks], pwh[cur][ks], acc[p], 0,0,0);
                acc[p] = __builtin_amdgcn_mfma_f32_16x16x32_bf16(xh[ks], pwl[cur][ks], acc[p], 0,0,0);
            }
        }
    }
#undef WOFF

    // ---- epilogue: single barrier, exchange pre2, combine ----
    if (g == 1) {
        #pragma unroll
        for (int p = 0; p < 7; ++p)
            *(f32x4*)&PW[((mt*7 + p)*64 + lane)*4] = acc[p];
    }
    __syncthreads();
    if (g == 0) {
        const int col = lane & 15, rg = lane >> 4;
        #pragma unroll
        for (int p = 0; p < 7; ++p) {
            int d = (start + p)*16 + col;
            if (d >= 200) continue;
            float bgd = bg[d], gbd = gbias[d];
            f32x4 p2 = *(const f32x4*)&PW[((mt*7 + p)*64 + lane)*4];
            #pragma unroll
            for (int r = 0; r < 4; ++r) {
                int e = e0 + mt*16 + rg*4 + r;
                if (e >= E) continue;
                float pre1 = acc[p][r] + bgd;
                float pre2 = p2[r] + gbd;
                float gt = sigmoidf_(pre2);
                float t  = tanhf_(pre1);
                float emb = emb_e[(size_t)e*200 + d];
                e2_emb[(size_t)e*200 + d] = (1.f - gt)*emb + gt*t;
            }
        }
    }
}

// ---------------------------------------------------------------------------
// K_q
// ---------------------------------------------------------------------------
__global__ __launch_bounds__(256) void q_kernel(
    const int* __restrict__ e1, const int* __restrict__ rel,
    const float* __restrict__ emb_rel, const float* __restrict__ e2_emb,
    float* __restrict__ q)
{
    int tid = threadIdx.x;
    for (int idx = tid; idx < B * D; idx += 256) {
        int b = idx / D, d = idx % D;
        q[idx] = e2_emb[(size_t)e1[b] * D + d] + emb_rel[(size_t)rel[b] * D + d];
    }
}

// ---------------------------------------------------------------------------
// GEMV via MFMA: 235 blocks x 128 e (2 chunks of 64), coalesced coeff staging.
// ---------------------------------------------------------------------------
constexpr int GVB = 235;

__global__ __launch_bounds__(256) void gemv_kernel(
    const int* __restrict__ e2m, const float* __restrict__ prob,
    const float* __restrict__ drop, const float* __restrict__ e2_emb,
    float* __restrict__ gpart)
{
    __shared__ unsigned short Bf[13312];                // [nt13][ks2][lane64][j8]
    __shared__ unsigned short Acp[2048], Acn[2048];     // [mtb2][ks2][lane64][j8]
    const int tid = threadIdx.x, lane = tid & 63, w = tid >> 6;
    const int e0 = blockIdx.x * 128;

    f32x4 acc[2][2][4];
    #pragma unroll
    for (int a = 0; a < 2; ++a)
        #pragma unroll
        for (int m = 0; m < 2; ++m)
            #pragma unroll
            for (int s = 0; s < 4; ++s) acc[a][m][s] = (f32x4){0.f,0.f,0.f,0.f};

    for (int c = 0; c < 2; ++c) {
        const int ec = e0 + c*64;
        if (c) __syncthreads();

        {
            const int bb = tid >> 3, part = tid & 7;
            const int eb = ec + part*8;
            float cp[8], cn[8];
            size_t base = (size_t)bb * E + eb;
            if (eb + 7 < E) {
                int4   m0 = *(const int4*)(e2m + base),   m1 = *(const int4*)(e2m + base + 4);
                float4 p0 = *(const float4*)(prob + base), p1 = *(const float4*)(prob + base + 4);
                float4 d0 = *(const float4*)(drop + base), d1 = *(const float4*)(drop + base + 4);
                cp[0]=m0.x?p0.x:0.f; cn[0]=m0.x?0.f:2.f*d0.x;
                cp[1]=m0.y?p0.y:0.f; cn[1]=m0.y?0.f:2.f*d0.y;
                cp[2]=m0.z?p0.z:0.f; cn[2]=m0.z?0.f:2.f*d0.z;
                cp[3]=m0.w?p0.w:0.f; cn[3]=m0.w?0.f:2.f*d0.w;
                cp[4]=m1.x?p1.x:0.f; cn[4]=m1.x?0.f:2.f*d1.x;
                cp[5]=m1.y?p1.y:0.f; cn[5]=m1.y?0.f:2.f*d1.y;
                cp[6]=m1.z?p1.z:0.f; cn[6]=m1.z?0.f:2.f*d1.z;
                cp[7]=m1.w?p1.w:0.f; cn[7]=m1.w?0.f:2.f*d1.w;
            } else {
                #pragma unroll
                for (int j = 0; j < 8; ++j) {
                    int e = eb + j;
                    cp[j] = 0.f; cn[j] = 0.f;
                    if (e < E) {
                        int m = e2m[base + j];
                        cp[j] = m ? prob[base + j] : 0.f;
                        cn[j] = m ? 0.f : 2.f * drop[base + j];
                    }
                }
            }
            short8 scp, scn;
            #pragma unroll
            for (int j = 0; j < 8; ++j) { scp[j] = (short)f2bf(cp[j]); scn[j] = (short)f2bf(cn[j]); }
            int off = (((bb >> 4)*2 + (part >> 2))*64 + ((bb & 15) | ((part & 3) << 4)))*8;
            *(short8*)&Acp[off] = scp;
            *(short8*)&Acn[off] = scn;
        }

        for (int s = tid; s < 3328; s += 256) {
            int el = s / 52, d4 = (s - el*52)*4;
            int e = ec + el;
            float4 f = make_float4(0.f,0.f,0.f,0.f);
            if (e < E && d4 < 200) f = *(const float4*)(e2_emb + (size_t)e*200 + d4);
            int ks = el >> 5, lp = (el >> 3) & 3, j = el & 7;
            float fv[4] = {f.x, f.y, f.z, f.w};
            #pragma unroll
            for (int z = 0; z < 4; ++z) {
                int d = d4 + z;
                Bf[(((d >> 4)*2 + ks)*64 + ((d & 15) | (lp << 4)))*8 + j] = f2bf(fv[z]);
            }
        }
        __syncthreads();

        short8 cpA[2][2], cnA[2][2];
        #pragma unroll
        for (int mtb = 0; mtb < 2; ++mtb)
            #pragma unroll
            for (int ks = 0; ks < 2; ++ks) {
                int fo = ((mtb*2 + ks)*64 + lane)*8;
                cpA[mtb][ks] = *(const short8*)&Acp[fo];
                cnA[mtb][ks] = *(const short8*)&Acn[fo];
            }
        #pragma unroll
        for (int ks = 0; ks < 2; ++ks)
            #pragma unroll
            for (int slot = 0; slot < 4; ++slot) {
                int nt = w + slot*4;
                if (nt < 13) {
                    short8 bf = *(const short8*)&Bf[((nt*2 + ks)*64 + lane)*8];
                    acc[0][0][slot] = __builtin_amdgcn_mfma_f32_16x16x32_bf16(cpA[0][ks], bf, acc[0][0][slot], 0,0,0);
                    acc[0][1][slot] = __builtin_amdgcn_mfma_f32_16x16x32_bf16(cpA[1][ks], bf, acc[0][1][slot], 0,0,0);
                    acc[1][0][slot] = __builtin_amdgcn_mfma_f32_16x16x32_bf16(cnA[0][ks], bf, acc[1][0][slot], 0,0,0);
                    acc[1][1][slot] = __builtin_amdgcn_mfma_f32_16x16x32_bf16(cnA[1][ks], bf, acc[1][1][slot], 0,0,0);
                }
            }
    }

    const int col = lane & 15, rg = lane >> 4;
    #pragma unroll
    for (int mat = 0; mat < 2; ++mat)
        #pragma unroll
        for (int mtb = 0; mtb < 2; ++mtb)
            #pragma unroll
            for (int slot = 0; slot < 4; ++slot) {
                int nt = w + slot*4;
                if (nt >= 13) continue;
                int d = nt*16 + col;
                if (d >= 200) continue;
                #pragma unroll
                for (int r = 0; r < 4; ++r) {
                    int b = mtb*16 + rg*4 + r;
                    gpart[(((size_t)blockIdx.x*2 + mat)*32 + b)*200 + d]
                        = acc[mat][mtb][slot][r];
                }
            }
}

// ---------------------------------------------------------------------------
// Reduce partials: posv/negv [32][200]
// ---------------------------------------------------------------------------
__global__ __launch_bounds__(128) void gred_kernel(
    const float* __restrict__ gpart, float* __restrict__ posv, float* __restrict__ negv)
{
    int o = blockIdx.x*128 + threadIdx.x;
    float sp = 0.f, sn = 0.f;
    #pragma unroll 4
    for (int blk = 0; blk < GVB; ++blk) {
        sp += gpart[((size_t)blk*2 + 0)*6400 + o];
        sn += gpart[((size_t)blk*2 + 1)*6400 + o];
    }
    posv[o] = sp;
    negv[o] = sn;
}

// ---------------------------------------------------------------------------
// Score v2: 469 blocks x 64 e, 512 thr (8 waves x 4 b).
//   e-rows in LDS pitch 204 (lane-stride 12 mod 32 -> conflict-free b128);
//   q read wave-uniform (scalarizable); no per-iteration barriers.
// ---------------------------------------------------------------------------
__global__ __launch_bounds__(512) void score_kernel(
    const float* __restrict__ q, const float* __restrict__ e2_emb,
    float* __restrict__ pred)
{
    __shared__ __align__(16) float Es[64*204];   // 52.2 KB
    const int tid = threadIdx.x, lane = tid & 63, w = tid >> 6;
    const int e0 = blockIdx.x * 64;

    for (int s = tid; s < 64*50; s += 512) {
        int er = s / 50, d4 = (s - er*50)*4;
        int e = e0 + er;
        float4 f = make_float4(0.f,0.f,0.f,0.f);
        if (e < E) f = *(const float4*)(e2_emb + (size_t)e*200 + d4);
        *(float4*)&Es[er*204 + d4] = f;
    }
    __syncthreads();

    const int b0 = w * 4;
    const float* erow = &Es[lane*204];
    float acc[4] = {0.f,0.f,0.f,0.f};
    #pragma unroll 5
    for (int dc = 0; dc < 200; dc += 8) {
        float4 ea = *(const float4*)(erow + dc);
        float4 eb = *(const float4*)(erow + dc + 4);
        #pragma unroll
        for (int i = 0; i < 4; ++i) {
            float4 qa = *(const float4*)(q + (b0+i)*200 + dc);
            float4 qb = *(const float4*)(q + (b0+i)*200 + dc + 4);
            acc[i] += fabsf(qa.x-ea.x) + fabsf(qa.y-ea.y) + fabsf(qa.z-ea.z) + fabsf(qa.w-ea.w)
                    + fabsf(qb.x-eb.x) + fabsf(qb.y-eb.y) + fabsf(qb.z-eb.z) + fabsf(qb.w-eb.w);
        }
    }
    int e = e0 + lane;
    if (e < E) {
        #pragma unroll
        for (int i = 0; i < 4; ++i)
            pred[(size_t)(b0+i)*E + e] = sigmoidf_(9.0f - acc[i]);
    }
}

// ---------------------------------------------------------------------------
// Final: fold psum8/isum8, means -> pos_s/neg_s -> loss
// ---------------------------------------------------------------------------
__global__ __launch_bounds__(256) void final_kernel(
    const int* __restrict__ e1, const float* __restrict__ q,
    const float* __restrict__ posv, const float* __restrict__ negv,
    const float* __restrict__ psum8, const float* __restrict__ isum8,
    const float* __restrict__ e2_emb, float* __restrict__ loss_out)
{
    const int tid = threadIdx.x;
    __shared__ float SP[32], SI[32];
    if (tid < 32) {
        float s = 0.f, t = 0.f;
        #pragma unroll
        for (int k = 0; k < 8; ++k) { s += psum8[tid*8 + k]; t += isum8[tid*8 + k]; }
        SP[tid] = s; SI[tid] = t;
    }
    __syncthreads();

    const int b = tid >> 3, dl = tid & 7;
    const int e1b = e1[b];
    const float isp = 1.f / SP[b];
    const float isn = 1.f / SI[b];
    float ps = 0.f, ns = 0.f;
    #pragma unroll
    for (int t = 0; t < 25; ++t) {
        int d = dl*25 + t;
        float e1e = e2_emb[(size_t)e1b*200 + d];
        float pm = 0.3f * (posv[b*200 + d] * isp) + 0.7f * e1e;
        float nm = 0.7f * (negv[b*200 + d] * isn) + 0.3f * e1e;
        float qv = q[b*200 + d];
        ps += fabsf(qv - pm);
        ns += fabsf(qv - nm);
    }
    ps += __shfl_down(ps, 4, 8); ps += __shfl_down(ps, 2, 8); ps += __shfl_down(ps, 1, 8);
    ns += __shfl_down(ns, 4, 8); ns += __shfl_down(ns, 2, 8); ns += __shfl_down(ns, 1, 8);

    __shared__ float PS[B], NS[B];
    if (dl == 0) { PS[b] = ps; NS[b] = ns; }
    __syncthreads();

    float part = 0.f;
    #pragma unroll
    for (int r = 0; r < 4; ++r) {
        int idx = tid + r*256;
        int i = idx >> 5, j = idx & 31;
        float x = NS[j] - PS[i];
        part += fminf(x, 0.f) - log1pf(expf(-fabsf(x)));
    }
    #pragma unroll
    for (int off = 32; off >= 1; off >>= 1) part += __shfl_down(part, off);
    __shared__ float wr[4];
    if ((tid & 63) == 0) wr[tid >> 6] = part;
    __syncthreads();
    if (tid == 0) loss_out[0] = -(wr[0] + wr[1] + wr[2] + wr[3]) * (1.f/1024.f);
}

// ---------------------------------------------------------------------------
extern "C" void kernel_launch(void* const* d_in, const int* in_sizes, int n_in,
                              void* d_out, int out_size, void* d_ws, size_t ws_size,
                              hipStream_t stream)
{
    const int*   e1      = (const int*)d_in[0];
    const int*   rel     = (const int*)d_in[1];
    const int*   e2m     = (const int*)d_in[2];
    const float* emb_e   = (const float*)d_in[3];
    const float* emb_rel = (const float*)d_in[4];
    const float* num_lit = (const float*)d_in[5];
    const float* Wg      = (const float*)d_in[6];
    const float* bg      = (const float*)d_in[7];
    const float* W1      = (const float*)d_in[8];
    const float* W2      = (const float*)d_in[9];
    const float* gbias   = (const float*)d_in[10];
    const float* prob    = (const float*)d_in[11];
    const float* drop    = (const float*)d_in[12];

    float* pred = (float*)d_out;
    float* ws   = (float*)d_ws;

    float*          e2_emb = ws;                                   // 6,000,000
    float*          q      = ws + 6000000;                         // 6,400
    unsigned short* whi    = (unsigned short*)(ws + 6006400);      // 106,496 us
    unsigned short* wlo    = (unsigned short*)(ws + 6059648);      // 106,496 us
    float*          gpart  = ws + 6112896;                         // 235*2*6400
    float*          posv   = ws + 9120896;                         // 6,400
    float*          negv   = ws + 9127296;                         // 6,400
    float*          psum8  = ws + 9133696;                         // 256
    float*          isum8  = ws + 9133952;                         // 256

    wprep_kernel<<<WELEMS/256, 256, 0, stream>>>(Wg, W1, W2, whi, wlo);
    sums_kernel<<<256, 256, 0, stream>>>(e2m, prob, psum8, isum8);
    gate_kernel<<<944, 512, 0, stream>>>(emb_e, num_lit, whi, wlo, bg, gbias, e2_emb);
    q_kernel<<<1, 256, 0, stream>>>(e1, rel, emb_rel, e2_emb, q);
    gemv_kernel<<<GVB, 256, 0, stream>>>(e2m, prob, drop, e2_emb, gpart);
    gred_kernel<<<50, 128, 0, stream>>>(gpart, posv, negv);
    score_kernel<<<(E + 63)/64, 512, 0, stream>>>(q, e2_emb, pred);
    final_kernel<<<1, 256, 0, stream>>>(e1, q, posv, negv, psum8, isum8, e2_emb,
                                        pred + (size_t)B*E);
}